// Round 7
// baseline (297.131 us; speedup 1.0000x reference)
//
#include <hip/hip_runtime.h>
#include <hip/hip_bf16.h>

// ---------------------------------------------------------------------------
// EncoderBlock on MI355X (gfx950). Round 20.
// r19 post-mortem: 2-phase stage-ahead GEMM reorder = null (284.7 vs 283.4)
// -- matches guide m233/m252: 2-phase critical path is stage+barrier
// overhead, unfixable by reordering; 8-phase only validated at 256²/8-wave.
// GEMM pool (~160-190 us at ~300 TF) is AT the expected perf for this
// structure/shape (m102 curve). r20 lever: WORK ELIMINATION via fusion.
// New gemm_ln kernel (BM=32 x BN=512 full-row, 512 thr / 8 waves, grid 256)
// computes O-proj and FFN2 with residual+LayerNorm in the epilogue
// (cross-wave row reduce via 2 KB LDS). Removes: ln1+ln2 launches, t and
// ff2 round-trips (16 MB wr + 32 MB rd), and keeps LN input in f32
// (closer to reference). 6 kernels total.
//
// ws layout (bytes), WS_NEED = 73416704, sentinel-guarded:
//   [0,        2097152)  wq|wk|wv|wo T (bf16)
//   [2097152,  4194304)  w1T
//   [4194304,  6291456)  w2T
//   [6291456, 14680064)  xcv: x as bf16 (8 MB)
//   [14680064,14696448)  small params (bf16)
//   A [14696448,23085056) qbuf (8 MB)
//   B [23085056,31473664) kbuf -> y             (8 MB)
//   C [31473664,39862272) vT                    (8 MB)
//   F [39862272,73416704) ff1 (32 MB)
//   d_out                attn output scratch (bf16) -> final output (fp32)
// ---------------------------------------------------------------------------

typedef __bf16 bf16;
typedef __bf16 bf16x4 __attribute__((ext_vector_type(4)));
typedef __bf16 bf16x8 __attribute__((ext_vector_type(8)));
typedef float  f32x4  __attribute__((ext_vector_type(4)));

#define NBATCH 4
#define SEQ    2048
#define DMODEL 512
#define NHEADS 8
#define DHEAD  64
#define DFF    2048
#define MTOT   (NBATCH * SEQ)   // 8192
#define WS_NEED 73416704u
#define QSCALE (0.125f * 1.44269504f)   // 1/sqrt(dk) * log2(e), folded into Q

__device__ __forceinline__ f32x4 mfma16(bf16x8 a, bf16x8 b, f32x4 c) {
    return __builtin_amdgcn_mfma_f32_16x16x32_bf16(a, b, c, 0, 0, 0);
}

// async global->LDS, 16 B/lane. LDS dest = wave-uniform base + lane*16.
__device__ __forceinline__ void lds16(const bf16* g, bf16* l) {
    __builtin_amdgcn_global_load_lds(
        (const __attribute__((address_space(1))) void*)g,
        (__attribute__((address_space(3))) void*)l, 16, 0, 0);
}

__device__ __forceinline__ float scrub(float f) {
    return (fabsf(f) < 1e30f) ? f : 0.f;   // NaN/Inf -> 0 (no-op valid data)
}

// T1 XCD-chunked swizzle for 2D GEMM grids (requires gx*gy % 8 == 0).
__device__ __forceinline__ void xcd_swizzle(int BMv, int BNv, int& mb, int& nb) {
    int gx = gridDim.x, gy = gridDim.y;
    int lin = blockIdx.y * gx + blockIdx.x;
    int q = (gx * gy) >> 3;
    lin = (lin & 7) * q + (lin >> 3);
    int mbi = lin / gy, nbi = lin - mbi * gy;
    mb = mbi * BMv; nb = nbi * BNv;
}

__global__ void sentinel_kernel(bf16* out) {
    out[threadIdx.x] = (bf16)1000.0f;
}

// ---------------------------------------------------------------------------
// prep: x convert + small-param converts + all 6 weight transposes, ONE launch
// ---------------------------------------------------------------------------
__global__ __launch_bounds__(256) void prep_kernel(
        const float* x,
        const float* wq, const float* wk, const float* wv, const float* wo,
        const float* w1, const float* w2,
        const float* bq, const float* bk, const float* bv, const float* bo,
        const float* b1, const float* b2,
        const float* l1a, const float* l1b, const float* l2a, const float* l2b,
        bf16* __restrict__ xcv,
        bf16* __restrict__ wT, bf16* __restrict__ w1T, bf16* __restrict__ w2T,
        bf16* __restrict__ prm) {
    __shared__ bf16 tile[32][33];
    int b = blockIdx.x;
    if (b < 4096) {
        int i = (b * 256 + threadIdx.x) * 4;
        float4 f = *(const float4*)(x + i);
        bf16x4 o = {(bf16)scrub(f.x), (bf16)scrub(f.y),
                    (bf16)scrub(f.z), (bf16)scrub(f.w)};
        *(bf16x4*)(xcv + i) = o;
        return;
    }
    if (b < 4106) {
        int pb = b - 4096;
        const float* srcs[10] = {bq, bk, bv, bo, b1, b2, l1a, l1b, l2a, l2b};
        const int len[10] = {512,512,512,512,2048,512,512,512,512,512};
        const int dst[10] = {0,512,1024,1536,2048,4096,4608,5120,5632,6144};
        const float* s = srcs[pb];
        bf16* d = prm + dst[pb];
        for (int i = threadIdx.x; i < len[pb]; i += 256)
            d[i] = (bf16)scrub(s[i]);
        return;
    }
    const float* in; bf16* out; int K, N, bx, by;
    if (b < 5130) {
        int idx = b - 4106, z = idx >> 8, rem = idx & 255;
        const float* srcs[4] = {wq, wk, wv, wo};
        in = srcs[z]; out = wT + (size_t)z * 262144;
        K = 512; N = 512; bx = rem & 15; by = rem >> 4;
    } else if (b < 6154) {
        int idx = b - 5130;
        in = w1; out = w1T; K = 512; N = 2048; bx = idx & 63; by = idx >> 6;
    } else {
        int idx = b - 6154;
        in = w2; out = w2T; K = 2048; N = 512; bx = idx & 15; by = idx >> 4;
    }
    int tx = threadIdx.x & 31, ty = threadIdx.x >> 5;
    int n0 = bx * 32, k0 = by * 32;
#pragma unroll
    for (int i = 0; i < 4; i++) {
        int kl = ty * 4 + i;
        tile[kl][tx] = (bf16)scrub(in[(size_t)(k0 + kl) * N + n0 + tx]);
    }
    __syncthreads();
#pragma unroll
    for (int i = 0; i < 4; i++) {
        int nl = ty * 4 + i;
        out[(size_t)(n0 + nl) * K + k0 + tx] = tile[tx][nl];
    }
}

// ---------------------------------------------------------------------------
// 128x128 GEMM, 2-phase stage-ahead pipeline over BK=32 slots. XCD-swizzled.
// Used for QKV-less plain GEMM (FFN1).
// ---------------------------------------------------------------------------
template <bool RELU>
__global__ __launch_bounds__(256) void gemm_bt(
        const bf16* __restrict__ A, const bf16* __restrict__ BT,
        const bf16* __restrict__ bias, bf16* __restrict__ Cout,
        int M, int N, int K) {
    constexpr int BM = 128, BN = 128;
    __shared__ __align__(16) bf16 As0[BM * 32], As1[BM * 32];
    __shared__ __align__(16) bf16 Bs0[BN * 32], Bs1[BN * 32];

    int tid  = threadIdx.x;
    int wid  = tid >> 6, lane = tid & 63;
    int quad = lane >> 4, l15 = lane & 15;
    int mb, nb;
    xcd_swizzle(BM, BN, mb, nb);
    int wm = (wid >> 1) * 64, wn = (wid & 1) * 64;

    f32x4 acc[4][4] = {};

    int c0 = wid * 128 + lane, c1 = c0 + 64;
    int ar0 = c0 >> 2, ac0 = (c0 & 3) * 8;
    int ar1 = c1 >> 2, ac1 = (c1 & 3) * 8;
    int o0 = wid * 1024, o1 = wid * 1024 + 512;

    lds16(&A [(size_t)(mb + ar0) * K + ac0], &As0[o0]);
    lds16(&A [(size_t)(mb + ar1) * K + ac1], &As0[o1]);
    lds16(&BT[(size_t)(nb + ar0) * K + ac0], &Bs0[o0]);
    lds16(&BT[(size_t)(nb + ar1) * K + ac1], &Bs0[o1]);
    __syncthreads();

    for (int k0 = 0; k0 < K; k0 += 64) {
        lds16(&A [(size_t)(mb + ar0) * K + k0 + 32 + ac0], &As1[o0]);
        lds16(&A [(size_t)(mb + ar1) * K + k0 + 32 + ac1], &As1[o1]);
        lds16(&BT[(size_t)(nb + ar0) * K + k0 + 32 + ac0], &Bs1[o0]);
        lds16(&BT[(size_t)(nb + ar1) * K + k0 + 32 + ac1], &Bs1[o1]);
        {
            bf16x8 af[4], bfr[4];
#pragma unroll
            for (int i = 0; i < 4; i++)
                af[i] = *(const bf16x8*)&As0[(wm + i * 16 + l15) * 32 + quad * 8];
#pragma unroll
            for (int j = 0; j < 4; j++)
                bfr[j] = *(const bf16x8*)&Bs0[(wn + j * 16 + l15) * 32 + quad * 8];
#pragma unroll
            for (int i = 0; i < 4; i++)
#pragma unroll
                for (int j = 0; j < 4; j++)
                    acc[i][j] = mfma16(af[i], bfr[j], acc[i][j]);
        }
        __syncthreads();
        if (k0 + 64 < K) {
            lds16(&A [(size_t)(mb + ar0) * K + k0 + 64 + ac0], &As0[o0]);
            lds16(&A [(size_t)(mb + ar1) * K + k0 + 64 + ac1], &As0[o1]);
            lds16(&BT[(size_t)(nb + ar0) * K + k0 + 64 + ac0], &Bs0[o0]);
            lds16(&BT[(size_t)(nb + ar1) * K + k0 + 64 + ac1], &Bs0[o1]);
        }
        {
            bf16x8 af[4], bfr[4];
#pragma unroll
            for (int i = 0; i < 4; i++)
                af[i] = *(const bf16x8*)&As1[(wm + i * 16 + l15) * 32 + quad * 8];
#pragma unroll
            for (int j = 0; j < 4; j++)
                bfr[j] = *(const bf16x8*)&Bs1[(wn + j * 16 + l15) * 32 + quad * 8];
#pragma unroll
            for (int i = 0; i < 4; i++)
#pragma unroll
                for (int j = 0; j < 4; j++)
                    acc[i][j] = mfma16(af[i], bfr[j], acc[i][j]);
        }
        __syncthreads();
    }

#pragma unroll
    for (int j = 0; j < 4; j++) {
        int n = nb + wn + j * 16 + l15;
        float bv = (float)bias[n];
#pragma unroll
        for (int i = 0; i < 4; i++) {
            int mBase = mb + wm + i * 16 + quad * 4;
#pragma unroll
            for (int r = 0; r < 4; r++) {
                float v = acc[i][j][r] + bv;
                if (RELU) v = v > 0.f ? v : 0.f;
                Cout[(size_t)(mBase + r) * N + n] = (bf16)v;
            }
        }
    }
}

// ---------------------------------------------------------------------------
// Fused GEMM + residual + LayerNorm. BM=32, BN=512 (full row), 512 threads
// = 8 waves x 64 cols. Grid = M/32 = 256 blocks. 2-phase stage-ahead
// K-loop (BK=32 slots). Epilogue: v = acc + bias + RES (f32); per-row
// sums via shfl within 16-lane groups + cross-wave LDS reduce; LN with
// unbiased std (ddof=1, eps added to std); out bf16 or f32.
// ---------------------------------------------------------------------------
__global__ __launch_bounds__(512) void gemm_ln(
        const bf16* __restrict__ A, const bf16* __restrict__ BT,
        const bf16* __restrict__ bias, const bf16* __restrict__ RES,
        const bf16* __restrict__ Al, const bf16* __restrict__ Bl,
        void* __restrict__ Out, int K, int final_out) {
    __shared__ __align__(16) bf16 As0[32 * 32],  As1[32 * 32];
    __shared__ __align__(16) bf16 Bs0[512 * 32], Bs1[512 * 32];
    __shared__ float red[8][32][2];

    int tid  = threadIdx.x;
    int wid  = tid >> 6, lane = tid & 63;
    int quad = lane >> 4, l15 = lane & 15;
    int mb = blockIdx.x * 32;

    f32x4 acc[2][4] = {};

    int srow = lane >> 2, scol = (lane & 3) * 8;

#define STAGE_LN(AS, BS, KO)                                                 \
    do {                                                                     \
        if (wid < 2)                                                         \
            lds16(&A[(size_t)(mb + wid * 16 + srow) * K + (KO) + scol],      \
                  &AS[wid * 16 * 32]);                                       \
        _Pragma("unroll")                                                    \
        for (int c = 0; c < 4; c++)                                          \
            lds16(&BT[(size_t)(c * 128 + wid * 16 + srow) * K + (KO) + scol],\
                  &BS[(c * 128 + wid * 16) * 32]);                           \
    } while (0)

#define COMP_LN(AS, BS)                                                      \
    do {                                                                     \
        bf16x8 af[2], bfr[4];                                                \
        _Pragma("unroll")                                                    \
        for (int i = 0; i < 2; i++)                                          \
            af[i] = *(const bf16x8*)&AS[(i * 16 + l15) * 32 + quad * 8];     \
        _Pragma("unroll")                                                    \
        for (int j = 0; j < 4; j++)                                          \
            bfr[j] = *(const bf16x8*)&BS[(wid * 64 + j * 16 + l15) * 32 +    \
                                         quad * 8];                          \
        _Pragma("unroll")                                                    \
        for (int i = 0; i < 2; i++)                                          \
            _Pragma("unroll")                                                \
            for (int j = 0; j < 4; j++)                                      \
                acc[i][j] = mfma16(af[i], bfr[j], acc[i][j]);                \
    } while (0)

    STAGE_LN(As0, Bs0, 0);
    __syncthreads();

    for (int k0 = 0; k0 < K; k0 += 64) {
        STAGE_LN(As1, Bs1, k0 + 32);   // flies across compute of slot0
        COMP_LN(As0, Bs0);
        __syncthreads();
        if (k0 + 64 < K)
            STAGE_LN(As0, Bs0, k0 + 64);  // flies across compute of slot1
        COMP_LN(As1, Bs1);
        __syncthreads();
    }
#undef STAGE_LN
#undef COMP_LN

    // ---- epilogue: bias + residual (f32) ----
    float vv[2][4][4];
#pragma unroll
    for (int i = 0; i < 2; i++)
#pragma unroll
        for (int j = 0; j < 4; j++) {
            int col = wid * 64 + j * 16 + l15;
            float bv = (float)bias[col];
#pragma unroll
            for (int r = 0; r < 4; r++) {
                size_t row = mb + i * 16 + quad * 4 + r;
                vv[i][j][r] = acc[i][j][r] + bv
                            + (float)RES[row * DMODEL + col];
            }
        }

    // per-row partials over this wave's 64 cols -> LDS
#pragma unroll
    for (int i = 0; i < 2; i++)
#pragma unroll
        for (int r = 0; r < 4; r++) {
            float s = 0.f, q = 0.f;
#pragma unroll
            for (int j = 0; j < 4; j++) {
                float v = vv[i][j][r];
                s += v; q += v * v;
            }
#pragma unroll
            for (int m = 1; m < 16; m <<= 1) {
                s += __shfl_xor(s, m);
                q += __shfl_xor(q, m);
            }
            if (l15 == 0) {
                int rowl = i * 16 + quad * 4 + r;
                red[wid][rowl][0] = s;
                red[wid][rowl][1] = q;
            }
        }
    __syncthreads();

    // cross-wave reduce + normalize + write
#pragma unroll
    for (int i = 0; i < 2; i++)
#pragma unroll
        for (int r = 0; r < 4; r++) {
            int rowl = i * 16 + quad * 4 + r;
            float s = 0.f, q = 0.f;
#pragma unroll
            for (int w = 0; w < 8; w++) {
                s += red[w][rowl][0];
                q += red[w][rowl][1];
            }
            float mean = s * (1.f / DMODEL);
            float var  = (q - DMODEL * mean * mean) * (1.f / (DMODEL - 1));
            var = var > 0.f ? var : 0.f;
            float inv = 1.f / (sqrtf(var) + 1e-6f);
            size_t row = mb + rowl;
#pragma unroll
            for (int j = 0; j < 4; j++) {
                int col = wid * 64 + j * 16 + l15;
                float yv = (float)Al[col] * (vv[i][j][r] - mean) * inv
                         + (float)Bl[col];
                yv = fminf(fmaxf(yv, -1e4f), 1e4f);
                if (final_out) ((float*)Out)[row * DMODEL + col] = yv;
                else           ((bf16*)Out)[row * DMODEL + col]  = (bf16)yv;
            }
        }
}

// ---------------------------------------------------------------------------
// Fused QKV GEMM, 2-phase stage-ahead pipeline; region 0 -> Q*(QSCALE),
// 1 -> K, 2 -> V^T via LDS-transposed coalesced epilogue. XCD-swizzled.
// ---------------------------------------------------------------------------
__global__ __launch_bounds__(256) void gemm_qkv(
        const bf16* __restrict__ A, const bf16* __restrict__ BT,
        const bf16* __restrict__ bias,
        bf16* __restrict__ Cq, bf16* __restrict__ Ck, bf16* __restrict__ Cv,
        int M, int N, int K) {
    constexpr int BM = 128, BN = 128;
    __shared__ __align__(16) bf16 As0[BM * 32], As1[BM * 32];
    __shared__ __align__(16) bf16 Bs0[BN * 32], Bs1[BN * 32];
    __shared__ __align__(16) bf16 Ts[128 * 136];

    int tid  = threadIdx.x;
    int wid  = tid >> 6, lane = tid & 63;
    int quad = lane >> 4, l15 = lane & 15;
    int mb, nb;
    xcd_swizzle(BM, BN, mb, nb);
    int wm = (wid >> 1) * 64, wn = (wid & 1) * 64;

    f32x4 acc[4][4] = {};

    int c0 = wid * 128 + lane, c1 = c0 + 64;
    int ar0 = c0 >> 2, ac0 = (c0 & 3) * 8;
    int ar1 = c1 >> 2, ac1 = (c1 & 3) * 8;
    int o0 = wid * 1024, o1 = wid * 1024 + 512;

    lds16(&A [(size_t)(mb + ar0) * K + ac0], &As0[o0]);
    lds16(&A [(size_t)(mb + ar1) * K + ac1], &As0[o1]);
    lds16(&BT[(size_t)(nb + ar0) * K + ac0], &Bs0[o0]);
    lds16(&BT[(size_t)(nb + ar1) * K + ac1], &Bs0[o1]);
    __syncthreads();

    for (int k0 = 0; k0 < K; k0 += 64) {
        lds16(&A [(size_t)(mb + ar0) * K + k0 + 32 + ac0], &As1[o0]);
        lds16(&A [(size_t)(mb + ar1) * K + k0 + 32 + ac1], &As1[o1]);
        lds16(&BT[(size_t)(nb + ar0) * K + k0 + 32 + ac0], &Bs1[o0]);
        lds16(&BT[(size_t)(nb + ar1) * K + k0 + 32 + ac1], &Bs1[o1]);
        {
            bf16x8 af[4], bfr[4];
#pragma unroll
            for (int i = 0; i < 4; i++)
                af[i] = *(const bf16x8*)&As0[(wm + i * 16 + l15) * 32 + quad * 8];
#pragma unroll
            for (int j = 0; j < 4; j++)
                bfr[j] = *(const bf16x8*)&Bs0[(wn + j * 16 + l15) * 32 + quad * 8];
#pragma unroll
            for (int i = 0; i < 4; i++)
#pragma unroll
                for (int j = 0; j < 4; j++)
                    acc[i][j] = mfma16(af[i], bfr[j], acc[i][j]);
        }
        __syncthreads();
        if (k0 + 64 < K) {
            lds16(&A [(size_t)(mb + ar0) * K + k0 + 64 + ac0], &As0[o0]);
            lds16(&A [(size_t)(mb + ar1) * K + k0 + 64 + ac1], &As0[o1]);
            lds16(&BT[(size_t)(nb + ar0) * K + k0 + 64 + ac0], &Bs0[o0]);
            lds16(&BT[(size_t)(nb + ar1) * K + k0 + 64 + ac1], &Bs0[o1]);
        }
        {
            bf16x8 af[4], bfr[4];
#pragma unroll
            for (int i = 0; i < 4; i++)
                af[i] = *(const bf16x8*)&As1[(wm + i * 16 + l15) * 32 + quad * 8];
#pragma unroll
            for (int j = 0; j < 4; j++)
                bfr[j] = *(const bf16x8*)&Bs1[(wn + j * 16 + l15) * 32 + quad * 8];
#pragma unroll
            for (int i = 0; i < 4; i++)
#pragma unroll
                for (int j = 0; j < 4; j++)
                    acc[i][j] = mfma16(af[i], bfr[j], acc[i][j]);
        }
        __syncthreads();
    }

    int reg = nb >> 9;   // 0=Q, 1=K, 2=V
    if (reg < 2) {
        bf16* C = reg ? Ck : Cq;
        float scl = reg ? 1.0f : QSCALE;
#pragma unroll
        for (int j = 0; j < 4; j++) {
            int n = nb + wn + j * 16 + l15;
            float bv = (float)bias[n];
            int nn = n & 511;
            int h = nn >> 6, dk = nn & 63;
#pragma unroll
            for (int i = 0; i < 4; i++) {
                int mBase = mb + wm + i * 16 + quad * 4;
#pragma unroll
                for (int r = 0; r < 4; r++) {
                    float v = (acc[i][j][r] + bv) * scl;
                    int m = mBase + r;
                    int b = m >> 11, s = m & (SEQ - 1);
                    C[((size_t)(b * NHEADS + h) * SEQ + s) * DHEAD + dk] = (bf16)v;
                }
            }
        }
    } else {
#pragma unroll
        for (int j = 0; j < 4; j++) {
            int nl = wn + j * 16 + l15;
            float bv = (float)bias[nb + nl];
#pragma unroll
            for (int i = 0; i < 4; i++) {
                int ml = wm + i * 16 + quad * 4;
                bf16x4 pk;
#pragma unroll
                for (int r = 0; r < 4; r++) pk[r] = (bf16)(acc[i][j][r] + bv);
                *(bf16x4*)&Ts[nl * 136 + ml] = pk;
            }
        }
        __syncthreads();
        int nl = tid >> 1, half = tid & 1;
        int nn = (nb + nl) & 511;
        int h = nn >> 6, dk = nn & 63;
        int bb = mb >> 11, s0 = mb & (SEQ - 1);
        bf16* dst = &Cv[((size_t)(bb * NHEADS + h) * DHEAD + dk) * SEQ + s0 + half * 64];
        const bf16* srcl = &Ts[nl * 136 + half * 64];
#pragma unroll
        for (int v = 0; v < 8; v++)
            *(uint4*)(dst + v * 8) = *(const uint4*)(srcl + v * 8);
    }
}

// ---------------------------------------------------------------------------
// Flash attention: grid (SEQ/128, B*H), block 256 = 4 waves, direct bf16 out.
// r15 staging structure (register-prefetch -> LDS double-buffer -> barrier);
// Pb stride 72; l-row via MFMA ones-trick; setprio; XCD swizzle.
// ---------------------------------------------------------------------------
__global__ __launch_bounds__(256) void attn_kernel(
        const bf16* __restrict__ Q, const bf16* __restrict__ K,
        const bf16* __restrict__ VT, bf16* __restrict__ Out) {
    __shared__ __align__(16) bf16 Ks[2][64 * 72];
    __shared__ __align__(16) bf16 Vs[2][64 * 72];
    __shared__ __align__(16) bf16 Pb[4][16 * 72];
    int tid  = threadIdx.x;
    int wid  = tid >> 6, lane = tid & 63;
    int quad = lane >> 4, l15 = lane & 15;

    int lin = blockIdx.y * 16 + blockIdx.x;        // grid is (16, 32)
    lin = (lin & 7) * 64 + (lin >> 3);             // bijective (512 = 8*64)
    int bh = lin >> 4;
    int qb = (lin & 15) * 128 + wid * 32;

    const bf16* Qh = Q  + (size_t)bh * SEQ * DHEAD;
    const bf16* Kh = K  + (size_t)bh * SEQ * DHEAD;
    const bf16* Vh = VT + (size_t)bh * DHEAD * SEQ;

    bf16x8 bQ0[2], bQ1[2];
#pragma unroll
    for (int c = 0; c < 2; c++) {
        const bf16* qp = &Qh[(qb + c * 16 + l15) * DHEAD + quad * 8];
        bQ0[c] = *(const bf16x8*)qp;
        bQ1[c] = *(const bf16x8*)(qp + 32);
    }

    bf16x8 vONE;
#pragma unroll
    for (int i = 0; i < 8; i++) vONE[i] = (bf16)1.0f;

    int cc0 = tid * 2, cc1 = cc0 + 1;
    int kr0 = cc0 >> 3, kc0 = (cc0 & 7) * 8;
    int kr1 = cc1 >> 3, kc1 = (cc1 & 7) * 8;

    f32x4 lacc[2] = {};
    f32x4 Oacc[2][4] = {};

    {
        uint4 ka0 = *(const uint4*)&Kh[(size_t)kr0 * DHEAD + kc0];
        uint4 ka1 = *(const uint4*)&Kh[(size_t)kr1 * DHEAD + kc1];
        uint4 va0 = *(const uint4*)&Vh[(size_t)kr0 * SEQ + kc0];
        uint4 va1 = *(const uint4*)&Vh[(size_t)kr1 * SEQ + kc1];
        *(uint4*)&Ks[0][kr0 * 72 + kc0] = ka0;
        *(uint4*)&Ks[0][kr1 * 72 + kc1] = ka1;
        *(uint4*)&Vs[0][kr0 * 72 + kc0] = va0;
        *(uint4*)&Vs[0][kr1 * 72 + kc1] = va1;
    }
    __syncthreads();

    for (int it = 0; it < SEQ / 64; it++) {
        int cur = it & 1, nxt = cur ^ 1;
        int kb = (it + 1) * 64;
        uint4 nk0, nk1, nv0, nv1;
        bool pf = (it + 1 < SEQ / 64);
        if (pf) {
            nk0 = *(const uint4*)&Kh[(size_t)(kb + kr0) * DHEAD + kc0];
            nk1 = *(const uint4*)&Kh[(size_t)(kb + kr1) * DHEAD + kc1];
            nv0 = *(const uint4*)&Vh[(size_t)kr0 * SEQ + kb + kc0];
            nv1 = *(const uint4*)&Vh[(size_t)kr1 * SEQ + kb + kc1];
        }

        bf16x8 aK0[4], aK1[4], bV0[4], bV1[4];
#pragma unroll
        for (int t = 0; t < 4; t++) {
            const bf16* kp = &Ks[cur][(t * 16 + l15) * 72 + quad * 8];
            aK0[t] = *(const bf16x8*)kp;
            aK1[t] = *(const bf16x8*)(kp + 32);
            const bf16* vp = &Vs[cur][(t * 16 + l15) * 72 + quad * 8];
            bV0[t] = *(const bf16x8*)vp;
            bV1[t] = *(const bf16x8*)(vp + 32);
        }

#pragma unroll
        for (int c = 0; c < 2; c++) {
            __builtin_amdgcn_s_setprio(1);
            f32x4 st[4];
#pragma unroll
            for (int t = 0; t < 4; t++) {
                f32x4 zv = {0.f, 0.f, 0.f, 0.f};
                st[t] = mfma16(aK1[t], bQ1[c], mfma16(aK0[t], bQ0[c], zv));
            }
            bf16* myP = Pb[wid];
#pragma unroll
            for (int t = 0; t < 4; t++) {
                bf16x4 pk;
#pragma unroll
                for (int r = 0; r < 4; r++)
                    pk[r] = (bf16)__builtin_amdgcn_exp2f(fminf(st[t][r], 60.f));
                *(bf16x4*)&myP[l15 * 72 + t * 16 + quad * 4] = pk;
            }
            // chain c+1's stores can't pass these reads (wave-local in-order DS)
            bf16x8 aP0 = *(const bf16x8*)&myP[l15 * 72 + quad * 8];
            bf16x8 aP1 = *(const bf16x8*)&myP[l15 * 72 + 32 + quad * 8];
#pragma unroll
            for (int nt = 0; nt < 4; nt++)
                Oacc[c][nt] = mfma16(aP1, bV1[nt],
                                     mfma16(aP0, bV0[nt], Oacc[c][nt]));
            // l-row via MFMA: P*1 sums keys; C/D row = quad*4+r matches Oacc.
            lacc[c] = mfma16(aP1, vONE, mfma16(aP0, vONE, lacc[c]));
            __builtin_amdgcn_s_setprio(0);
        }

        if (pf) {
            *(uint4*)&Ks[nxt][kr0 * 72 + kc0] = nk0;
            *(uint4*)&Ks[nxt][kr1 * 72 + kc1] = nk1;
            *(uint4*)&Vs[nxt][kr0 * 72 + kc0] = nv0;
            *(uint4*)&Vs[nxt][kr1 * 72 + kc1] = nv1;
        }
        __syncthreads();
    }

    int b = bh >> 3, hd = bh & 7;
#pragma unroll
    for (int c = 0; c < 2; c++) {
        float linv[4];
#pragma unroll
        for (int r = 0; r < 4; r++)
            linv[r] = 1.f / lacc[c][r];
#pragma unroll
        for (int nt = 0; nt < 4; nt++)
#pragma unroll
            for (int r = 0; r < 4; r++) {
                int s = qb + c * 16 + quad * 4 + r;
                Out[((size_t)(b * SEQ + s)) * DMODEL + hd * 64 + nt * 16 + l15]
                    = (bf16)(Oacc[c][nt][r] * linv[r]);
            }
    }
}

// ---------------------------------------------------------------------------
extern "C" void kernel_launch(void* const* d_in, const int* in_sizes, int n_in,
                              void* d_out, int out_size, void* d_ws, size_t ws_size,
                              hipStream_t stream) {
    if (ws_size < WS_NEED) {
        sentinel_kernel<<<1, 64, 0, stream>>>((bf16*)d_out);
        return;
    }

    const float* x  = (const float*)d_in[0];
    const float* wq = (const float*)d_in[1],  *bq = (const float*)d_in[2];
    const float* wk = (const float*)d_in[3],  *bk = (const float*)d_in[4];
    const float* wv = (const float*)d_in[5],  *bv = (const float*)d_in[6];
    const float* wo = (const float*)d_in[7],  *bo = (const float*)d_in[8];
    const float* w1 = (const float*)d_in[9],  *b1 = (const float*)d_in[10];
    const float* w2 = (const float*)d_in[11], *b2 = (const float*)d_in[12];
    const float* ln1a = (const float*)d_in[13], *ln1b = (const float*)d_in[14];
    const float* ln2a = (const float*)d_in[15], *ln2b = (const float*)d_in[16];

    char* ws = (char*)d_ws;
    bf16* wT   = (bf16*)(ws + 0);
    bf16* woT  = (bf16*)(ws + 1572864);
    bf16* w1T  = (bf16*)(ws + 2097152);
    bf16* w2T  = (bf16*)(ws + 4194304);
    bf16* xcv  = (bf16*)(ws + 6291456);
    bf16* prm  = (bf16*)(ws + 14680064);
    bf16* regA = (bf16*)(ws + 14696448);
    bf16* regB = (bf16*)(ws + 23085056);
    bf16* regC = (bf16*)(ws + 31473664);
    bf16* ff1  = (bf16*)(ws + 39862272);
    bf16* aout = (bf16*)d_out;   // scratch (fully overwritten by final gemm_ln)

    bf16 *pbq = prm, *pbo = prm + 1536;
    bf16 *pb1 = prm + 2048, *pb2 = prm + 4096;
    bf16 *pl1a = prm + 4608, *pl1b = prm + 5120;
    bf16 *pl2a = prm + 5632, *pl2b = prm + 6144;

    prep_kernel<<<7178, 256, 0, stream>>>(x, wq, wk, wv, wo, w1, w2,
                                          bq, bk, bv, bo, b1, b2,
                                          ln1a, ln1b, ln2a, ln2b,
                                          xcv, wT, w1T, w2T, prm);

    // fused QKV projection (Q pre-scaled by QSCALE; V^T coalesced epilogue)
    gemm_qkv<<<dim3(64, 12), 256, 0, stream>>>(xcv, wT, pbq,
                                               regA, regB, regC,
                                               MTOT, 3 * DMODEL, DMODEL);

    // attention -> d_out (scratch), direct bf16
    attn_kernel<<<dim3(SEQ / 128, NBATCH * NHEADS), 256, 0, stream>>>(
        regA, regB, regC, aout);

    // fused O-proj + residual(x) + LN1 -> y (regB, bf16)
    gemm_ln<<<256, 512, 0, stream>>>(aout, woT, pbo, xcv, pl1a, pl1b,
                                     regB, DMODEL, 0);

    // FFN1: y -> ff1 (ReLU)
    gemm_bt<true><<<dim3(64, 16), 256, 0, stream>>>(regB, w1T, pb1, ff1,
                                                    MTOT, DFF, DMODEL);

    // fused FFN2 + residual(y) + LN2 -> out (fp32)
    gemm_ln<<<256, 512, 0, stream>>>(ff1, w2T, pb2, regB, pl2a, pl2b,
                                     d_out, DFF, 1);
}

// Round 8
// 277.917 us; speedup vs baseline: 1.0691x; 1.0691x over previous
//
#include <hip/hip_runtime.h>
#include <hip/hip_bf16.h>

// ---------------------------------------------------------------------------
// EncoderBlock on MI355X (gfx950). Round 21.
// r20 post-mortem: gemm_ln full-row fusion REGRESSED (297 vs 283): BN=512
// tiles stage the whole B matrix per block (FFN2: 256 blocks x 2MB = 512MB
// VMEM->LDS ~ 85us) to save ~8us of LN. Reverted to r17/r19 structure.
// r21 lever: attn LDS bank conflicts (7.34M cyc = 18% of attn CU-time;
// K/V frag reads ~4.2M, P roundtrip ~3.15M). Stride-72 frag reads fold 64
// lanes into 8 bank-quads x 8 rows (serialized b128). Fix per m214/G4:
// stride 64 elems (128B rows) + XOR swizzle chunk^=(row&7) on BOTH LDS
// write and read sides (reg-staged, so both sides controllable). Plus
// manual 2x unroll of the K-tile loop (static buffer indices -> address
// hoisting). GEMMs/ln back to r19 forms.
//
// ws layout (bytes), WS_NEED = 73416704, sentinel-guarded:
//   [0,        2097152)  wq|wk|wv|wo T (bf16)
//   [2097152,  4194304)  w1T
//   [4194304,  6291456)  w2T
//   [6291456, 14680064)  xcv: x as bf16 (8 MB)
//   [14680064,14696448)  small params (bf16)
//   A [14696448,23085056) qbuf -> t -> ff2      (8 MB)
//   B [23085056,31473664) kbuf -> y             (8 MB)
//   C [31473664,39862272) vT                    (8 MB)
//   F [39862272,73416704) ff1 (32 MB)
//   d_out                attn output scratch (bf16) -> final output (fp32)
// ---------------------------------------------------------------------------

typedef __bf16 bf16;
typedef __bf16 bf16x4 __attribute__((ext_vector_type(4)));
typedef __bf16 bf16x8 __attribute__((ext_vector_type(8)));
typedef float  f32x4  __attribute__((ext_vector_type(4)));

#define NBATCH 4
#define SEQ    2048
#define DMODEL 512
#define NHEADS 8
#define DHEAD  64
#define DFF    2048
#define MTOT   (NBATCH * SEQ)   // 8192
#define WS_NEED 73416704u
#define QSCALE (0.125f * 1.44269504f)   // 1/sqrt(dk) * log2(e), folded into Q

__device__ __forceinline__ f32x4 mfma16(bf16x8 a, bf16x8 b, f32x4 c) {
    return __builtin_amdgcn_mfma_f32_16x16x32_bf16(a, b, c, 0, 0, 0);
}

// async global->LDS, 16 B/lane. LDS dest = wave-uniform base + lane*16.
__device__ __forceinline__ void lds16(const bf16* g, bf16* l) {
    __builtin_amdgcn_global_load_lds(
        (const __attribute__((address_space(1))) void*)g,
        (__attribute__((address_space(3))) void*)l, 16, 0, 0);
}

__device__ __forceinline__ float scrub(float f) {
    return (fabsf(f) < 1e30f) ? f : 0.f;   // NaN/Inf -> 0 (no-op valid data)
}

// T1 XCD-chunked swizzle for 2D GEMM grids (requires gx*gy % 8 == 0).
__device__ __forceinline__ void xcd_swizzle(int BMv, int BNv, int& mb, int& nb) {
    int gx = gridDim.x, gy = gridDim.y;
    int lin = blockIdx.y * gx + blockIdx.x;
    int q = (gx * gy) >> 3;
    lin = (lin & 7) * q + (lin >> 3);
    int mbi = lin / gy, nbi = lin - mbi * gy;
    mb = mbi * BMv; nb = nbi * BNv;
}

__global__ void sentinel_kernel(bf16* out) {
    out[threadIdx.x] = (bf16)1000.0f;
}

// ---------------------------------------------------------------------------
// prep: x convert + small-param converts + all 6 weight transposes, ONE launch
// ---------------------------------------------------------------------------
__global__ __launch_bounds__(256) void prep_kernel(
        const float* x,
        const float* wq, const float* wk, const float* wv, const float* wo,
        const float* w1, const float* w2,
        const float* bq, const float* bk, const float* bv, const float* bo,
        const float* b1, const float* b2,
        const float* l1a, const float* l1b, const float* l2a, const float* l2b,
        bf16* __restrict__ xcv,
        bf16* __restrict__ wT, bf16* __restrict__ w1T, bf16* __restrict__ w2T,
        bf16* __restrict__ prm) {
    __shared__ bf16 tile[32][33];
    int b = blockIdx.x;
    if (b < 4096) {
        int i = (b * 256 + threadIdx.x) * 4;
        float4 f = *(const float4*)(x + i);
        bf16x4 o = {(bf16)scrub(f.x), (bf16)scrub(f.y),
                    (bf16)scrub(f.z), (bf16)scrub(f.w)};
        *(bf16x4*)(xcv + i) = o;
        return;
    }
    if (b < 4106) {
        int pb = b - 4096;
        const float* srcs[10] = {bq, bk, bv, bo, b1, b2, l1a, l1b, l2a, l2b};
        const int len[10] = {512,512,512,512,2048,512,512,512,512,512};
        const int dst[10] = {0,512,1024,1536,2048,4096,4608,5120,5632,6144};
        const float* s = srcs[pb];
        bf16* d = prm + dst[pb];
        for (int i = threadIdx.x; i < len[pb]; i += 256)
            d[i] = (bf16)scrub(s[i]);
        return;
    }
    const float* in; bf16* out; int K, N, bx, by;
    if (b < 5130) {
        int idx = b - 4106, z = idx >> 8, rem = idx & 255;
        const float* srcs[4] = {wq, wk, wv, wo};
        in = srcs[z]; out = wT + (size_t)z * 262144;
        K = 512; N = 512; bx = rem & 15; by = rem >> 4;
    } else if (b < 6154) {
        int idx = b - 5130;
        in = w1; out = w1T; K = 512; N = 2048; bx = idx & 63; by = idx >> 6;
    } else {
        int idx = b - 6154;
        in = w2; out = w2T; K = 2048; N = 512; bx = idx & 15; by = idx >> 4;
    }
    int tx = threadIdx.x & 31, ty = threadIdx.x >> 5;
    int n0 = bx * 32, k0 = by * 32;
#pragma unroll
    for (int i = 0; i < 4; i++) {
        int kl = ty * 4 + i;
        tile[kl][tx] = (bf16)scrub(in[(size_t)(k0 + kl) * N + n0 + tx]);
    }
    __syncthreads();
#pragma unroll
    for (int i = 0; i < 4; i++) {
        int nl = ty * 4 + i;
        out[(size_t)(n0 + nl) * K + k0 + tx] = tile[tx][nl];
    }
}

// ---------------------------------------------------------------------------
// 128x128 GEMM, 2-phase stage-ahead pipeline over BK=32 slots. XCD-swizzled.
// ---------------------------------------------------------------------------
template <bool RELU>
__global__ __launch_bounds__(256) void gemm_bt(
        const bf16* __restrict__ A, const bf16* __restrict__ BT,
        const bf16* __restrict__ bias, bf16* __restrict__ Cout,
        int M, int N, int K) {
    constexpr int BM = 128, BN = 128;
    __shared__ __align__(16) bf16 As0[BM * 32], As1[BM * 32];
    __shared__ __align__(16) bf16 Bs0[BN * 32], Bs1[BN * 32];

    int tid  = threadIdx.x;
    int wid  = tid >> 6, lane = tid & 63;
    int quad = lane >> 4, l15 = lane & 15;
    int mb, nb;
    xcd_swizzle(BM, BN, mb, nb);
    int wm = (wid >> 1) * 64, wn = (wid & 1) * 64;

    f32x4 acc[4][4] = {};

    int c0 = wid * 128 + lane, c1 = c0 + 64;
    int ar0 = c0 >> 2, ac0 = (c0 & 3) * 8;
    int ar1 = c1 >> 2, ac1 = (c1 & 3) * 8;
    int o0 = wid * 1024, o1 = wid * 1024 + 512;

    lds16(&A [(size_t)(mb + ar0) * K + ac0], &As0[o0]);
    lds16(&A [(size_t)(mb + ar1) * K + ac1], &As0[o1]);
    lds16(&BT[(size_t)(nb + ar0) * K + ac0], &Bs0[o0]);
    lds16(&BT[(size_t)(nb + ar1) * K + ac1], &Bs0[o1]);
    __syncthreads();

    for (int k0 = 0; k0 < K; k0 += 64) {
        lds16(&A [(size_t)(mb + ar0) * K + k0 + 32 + ac0], &As1[o0]);
        lds16(&A [(size_t)(mb + ar1) * K + k0 + 32 + ac1], &As1[o1]);
        lds16(&BT[(size_t)(nb + ar0) * K + k0 + 32 + ac0], &Bs1[o0]);
        lds16(&BT[(size_t)(nb + ar1) * K + k0 + 32 + ac1], &Bs1[o1]);
        {
            bf16x8 af[4], bfr[4];
#pragma unroll
            for (int i = 0; i < 4; i++)
                af[i] = *(const bf16x8*)&As0[(wm + i * 16 + l15) * 32 + quad * 8];
#pragma unroll
            for (int j = 0; j < 4; j++)
                bfr[j] = *(const bf16x8*)&Bs0[(wn + j * 16 + l15) * 32 + quad * 8];
#pragma unroll
            for (int i = 0; i < 4; i++)
#pragma unroll
                for (int j = 0; j < 4; j++)
                    acc[i][j] = mfma16(af[i], bfr[j], acc[i][j]);
        }
        __syncthreads();
        if (k0 + 64 < K) {
            lds16(&A [(size_t)(mb + ar0) * K + k0 + 64 + ac0], &As0[o0]);
            lds16(&A [(size_t)(mb + ar1) * K + k0 + 64 + ac1], &As0[o1]);
            lds16(&BT[(size_t)(nb + ar0) * K + k0 + 64 + ac0], &Bs0[o0]);
            lds16(&BT[(size_t)(nb + ar1) * K + k0 + 64 + ac1], &Bs0[o1]);
        }
        {
            bf16x8 af[4], bfr[4];
#pragma unroll
            for (int i = 0; i < 4; i++)
                af[i] = *(const bf16x8*)&As1[(wm + i * 16 + l15) * 32 + quad * 8];
#pragma unroll
            for (int j = 0; j < 4; j++)
                bfr[j] = *(const bf16x8*)&Bs1[(wn + j * 16 + l15) * 32 + quad * 8];
#pragma unroll
            for (int i = 0; i < 4; i++)
#pragma unroll
                for (int j = 0; j < 4; j++)
                    acc[i][j] = mfma16(af[i], bfr[j], acc[i][j]);
        }
        __syncthreads();
    }

#pragma unroll
    for (int j = 0; j < 4; j++) {
        int n = nb + wn + j * 16 + l15;
        float bv = (float)bias[n];
#pragma unroll
        for (int i = 0; i < 4; i++) {
            int mBase = mb + wm + i * 16 + quad * 4;
#pragma unroll
            for (int r = 0; r < 4; r++) {
                float v = acc[i][j][r] + bv;
                if (RELU) v = v > 0.f ? v : 0.f;
                Cout[(size_t)(mBase + r) * N + n] = (bf16)v;
            }
        }
    }
}

// ---------------------------------------------------------------------------
// BM=64, BN=128 GEMM, 2-phase stage-ahead pipeline. For O-proj / FFN2.
// ---------------------------------------------------------------------------
template <bool RELU>
__global__ __launch_bounds__(256) void gemm_bt64(
        const bf16* __restrict__ A, const bf16* __restrict__ BT,
        const bf16* __restrict__ bias, bf16* __restrict__ Cout,
        int M, int N, int K) {
    constexpr int BM = 64, BN = 128;
    __shared__ __align__(16) bf16 As0[BM * 32], As1[BM * 32];
    __shared__ __align__(16) bf16 Bs0[BN * 32], Bs1[BN * 32];

    int tid  = threadIdx.x;
    int wid  = tid >> 6, lane = tid & 63;
    int quad = lane >> 4, l15 = lane & 15;
    int mb, nb;
    xcd_swizzle(BM, BN, mb, nb);
    int wm = (wid >> 1) * 32, wn = (wid & 1) * 64;

    f32x4 acc[2][4] = {};

    int cA = wid * 64 + lane;
    int arA = cA >> 2, acA = (cA & 3) * 8;
    int cB0 = wid * 128 + lane, cB1 = cB0 + 64;
    int br0 = cB0 >> 2, bc0 = (cB0 & 3) * 8;
    int br1 = cB1 >> 2, bc1 = (cB1 & 3) * 8;

    lds16(&A [(size_t)(mb + arA) * K + acA], &As0[wid * 512]);
    lds16(&BT[(size_t)(nb + br0) * K + bc0], &Bs0[wid * 1024]);
    lds16(&BT[(size_t)(nb + br1) * K + bc1], &Bs0[wid * 1024 + 512]);
    __syncthreads();

    for (int k0 = 0; k0 < K; k0 += 64) {
        lds16(&A [(size_t)(mb + arA) * K + k0 + 32 + acA], &As1[wid * 512]);
        lds16(&BT[(size_t)(nb + br0) * K + k0 + 32 + bc0], &Bs1[wid * 1024]);
        lds16(&BT[(size_t)(nb + br1) * K + k0 + 32 + bc1], &Bs1[wid * 1024 + 512]);
        {
            bf16x8 a0[2], b0[4];
#pragma unroll
            for (int i = 0; i < 2; i++)
                a0[i] = *(const bf16x8*)&As0[(wm + i * 16 + l15) * 32 + quad * 8];
#pragma unroll
            for (int j = 0; j < 4; j++)
                b0[j] = *(const bf16x8*)&Bs0[(wn + j * 16 + l15) * 32 + quad * 8];
#pragma unroll
            for (int i = 0; i < 2; i++)
#pragma unroll
                for (int j = 0; j < 4; j++)
                    acc[i][j] = mfma16(a0[i], b0[j], acc[i][j]);
        }
        __syncthreads();
        if (k0 + 64 < K) {
            lds16(&A [(size_t)(mb + arA) * K + k0 + 64 + acA], &As0[wid * 512]);
            lds16(&BT[(size_t)(nb + br0) * K + k0 + 64 + bc0], &Bs0[wid * 1024]);
            lds16(&BT[(size_t)(nb + br1) * K + k0 + 64 + bc1], &Bs0[wid * 1024 + 512]);
        }
        {
            bf16x8 a1[2], b1[4];
#pragma unroll
            for (int i = 0; i < 2; i++)
                a1[i] = *(const bf16x8*)&As1[(wm + i * 16 + l15) * 32 + quad * 8];
#pragma unroll
            for (int j = 0; j < 4; j++)
                b1[j] = *(const bf16x8*)&Bs1[(wn + j * 16 + l15) * 32 + quad * 8];
#pragma unroll
            for (int i = 0; i < 2; i++)
#pragma unroll
                for (int j = 0; j < 4; j++)
                    acc[i][j] = mfma16(a1[i], b1[j], acc[i][j]);
        }
        __syncthreads();
    }

#pragma unroll
    for (int j = 0; j < 4; j++) {
        int n = nb + wn + j * 16 + l15;
        float bv = (float)bias[n];
#pragma unroll
        for (int i = 0; i < 2; i++) {
            int mBase = mb + wm + i * 16 + quad * 4;
#pragma unroll
            for (int r = 0; r < 4; r++) {
                float v = acc[i][j][r] + bv;
                if (RELU) v = v > 0.f ? v : 0.f;
                Cout[(size_t)(mBase + r) * N + n] = (bf16)v;
            }
        }
    }
}

// ---------------------------------------------------------------------------
// Fused QKV GEMM, 2-phase stage-ahead pipeline; region 0 -> Q*(QSCALE),
// 1 -> K, 2 -> V^T via LDS-transposed coalesced epilogue. XCD-swizzled.
// ---------------------------------------------------------------------------
__global__ __launch_bounds__(256) void gemm_qkv(
        const bf16* __restrict__ A, const bf16* __restrict__ BT,
        const bf16* __restrict__ bias,
        bf16* __restrict__ Cq, bf16* __restrict__ Ck, bf16* __restrict__ Cv,
        int M, int N, int K) {
    constexpr int BM = 128, BN = 128;
    __shared__ __align__(16) bf16 As0[BM * 32], As1[BM * 32];
    __shared__ __align__(16) bf16 Bs0[BN * 32], Bs1[BN * 32];
    __shared__ __align__(16) bf16 Ts[128 * 136];

    int tid  = threadIdx.x;
    int wid  = tid >> 6, lane = tid & 63;
    int quad = lane >> 4, l15 = lane & 15;
    int mb, nb;
    xcd_swizzle(BM, BN, mb, nb);
    int wm = (wid >> 1) * 64, wn = (wid & 1) * 64;

    f32x4 acc[4][4] = {};

    int c0 = wid * 128 + lane, c1 = c0 + 64;
    int ar0 = c0 >> 2, ac0 = (c0 & 3) * 8;
    int ar1 = c1 >> 2, ac1 = (c1 & 3) * 8;
    int o0 = wid * 1024, o1 = wid * 1024 + 512;

    lds16(&A [(size_t)(mb + ar0) * K + ac0], &As0[o0]);
    lds16(&A [(size_t)(mb + ar1) * K + ac1], &As0[o1]);
    lds16(&BT[(size_t)(nb + ar0) * K + ac0], &Bs0[o0]);
    lds16(&BT[(size_t)(nb + ar1) * K + ac1], &Bs0[o1]);
    __syncthreads();

    for (int k0 = 0; k0 < K; k0 += 64) {
        lds16(&A [(size_t)(mb + ar0) * K + k0 + 32 + ac0], &As1[o0]);
        lds16(&A [(size_t)(mb + ar1) * K + k0 + 32 + ac1], &As1[o1]);
        lds16(&BT[(size_t)(nb + ar0) * K + k0 + 32 + ac0], &Bs1[o0]);
        lds16(&BT[(size_t)(nb + ar1) * K + k0 + 32 + ac1], &Bs1[o1]);
        {
            bf16x8 af[4], bfr[4];
#pragma unroll
            for (int i = 0; i < 4; i++)
                af[i] = *(const bf16x8*)&As0[(wm + i * 16 + l15) * 32 + quad * 8];
#pragma unroll
            for (int j = 0; j < 4; j++)
                bfr[j] = *(const bf16x8*)&Bs0[(wn + j * 16 + l15) * 32 + quad * 8];
#pragma unroll
            for (int i = 0; i < 4; i++)
#pragma unroll
                for (int j = 0; j < 4; j++)
                    acc[i][j] = mfma16(af[i], bfr[j], acc[i][j]);
        }
        __syncthreads();
        if (k0 + 64 < K) {
            lds16(&A [(size_t)(mb + ar0) * K + k0 + 64 + ac0], &As0[o0]);
            lds16(&A [(size_t)(mb + ar1) * K + k0 + 64 + ac1], &As0[o1]);
            lds16(&BT[(size_t)(nb + ar0) * K + k0 + 64 + ac0], &Bs0[o0]);
            lds16(&BT[(size_t)(nb + ar1) * K + k0 + 64 + ac1], &Bs0[o1]);
        }
        {
            bf16x8 af[4], bfr[4];
#pragma unroll
            for (int i = 0; i < 4; i++)
                af[i] = *(const bf16x8*)&As1[(wm + i * 16 + l15) * 32 + quad * 8];
#pragma unroll
            for (int j = 0; j < 4; j++)
                bfr[j] = *(const bf16x8*)&Bs1[(wn + j * 16 + l15) * 32 + quad * 8];
#pragma unroll
            for (int i = 0; i < 4; i++)
#pragma unroll
                for (int j = 0; j < 4; j++)
                    acc[i][j] = mfma16(af[i], bfr[j], acc[i][j]);
        }
        __syncthreads();
    }

    int reg = nb >> 9;   // 0=Q, 1=K, 2=V
    if (reg < 2) {
        bf16* C = reg ? Ck : Cq;
        float scl = reg ? 1.0f : QSCALE;
#pragma unroll
        for (int j = 0; j < 4; j++) {
            int n = nb + wn + j * 16 + l15;
            float bv = (float)bias[n];
            int nn = n & 511;
            int h = nn >> 6, dk = nn & 63;
#pragma unroll
            for (int i = 0; i < 4; i++) {
                int mBase = mb + wm + i * 16 + quad * 4;
#pragma unroll
                for (int r = 0; r < 4; r++) {
                    float v = (acc[i][j][r] + bv) * scl;
                    int m = mBase + r;
                    int b = m >> 11, s = m & (SEQ - 1);
                    C[((size_t)(b * NHEADS + h) * SEQ + s) * DHEAD + dk] = (bf16)v;
                }
            }
        }
    } else {
#pragma unroll
        for (int j = 0; j < 4; j++) {
            int nl = wn + j * 16 + l15;
            float bv = (float)bias[nb + nl];
#pragma unroll
            for (int i = 0; i < 4; i++) {
                int ml = wm + i * 16 + quad * 4;
                bf16x4 pk;
#pragma unroll
                for (int r = 0; r < 4; r++) pk[r] = (bf16)(acc[i][j][r] + bv);
                *(bf16x4*)&Ts[nl * 136 + ml] = pk;
            }
        }
        __syncthreads();
        int nl = tid >> 1, half = tid & 1;
        int nn = (nb + nl) & 511;
        int h = nn >> 6, dk = nn & 63;
        int bb = mb >> 11, s0 = mb & (SEQ - 1);
        bf16* dst = &Cv[((size_t)(bb * NHEADS + h) * DHEAD + dk) * SEQ + s0 + half * 64];
        const bf16* srcl = &Ts[nl * 136 + half * 64];
#pragma unroll
        for (int v = 0; v < 8; v++)
            *(uint4*)(dst + v * 8) = *(const uint4*)(srcl + v * 8);
    }
}

// ---------------------------------------------------------------------------
// Flash attention: grid (16, 32), block 256 = 4 waves, direct bf16 out.
// r15 staging structure; r21: stride-64 (128B) K/V/P rows with XOR swizzle
// chunk ^= (row&7) on both LDS write and read sides (m214/G4 recipe --
// stride-72 frag reads folded 64 lanes into 8 bank-quads x 8 rows), and
// manual 2x unroll of the K-tile loop (static buffer indices).
// ---------------------------------------------------------------------------
__global__ __launch_bounds__(256) void attn_kernel(
        const bf16* __restrict__ Q, const bf16* __restrict__ K,
        const bf16* __restrict__ VT, bf16* __restrict__ Out) {
    __shared__ __align__(16) bf16 Ks[2][64 * 64];
    __shared__ __align__(16) bf16 Vs[2][64 * 64];
    __shared__ __align__(16) bf16 Pb[4][16 * 64];
    int tid  = threadIdx.x;
    int wid  = tid >> 6, lane = tid & 63;
    int quad = lane >> 4, l15 = lane & 15;

    int lin = blockIdx.y * 16 + blockIdx.x;        // grid is (16, 32)
    lin = (lin & 7) * 64 + (lin >> 3);             // bijective (512 = 8*64)
    int bh = lin >> 4;
    int qb = (lin & 15) * 128 + wid * 32;

    const bf16* Qh = Q  + (size_t)bh * SEQ * DHEAD;
    const bf16* Kh = K  + (size_t)bh * SEQ * DHEAD;
    const bf16* Vh = VT + (size_t)bh * DHEAD * SEQ;

    bf16x8 bQ0[2], bQ1[2];
#pragma unroll
    for (int c = 0; c < 2; c++) {
        const bf16* qp = &Qh[(qb + c * 16 + l15) * DHEAD + quad * 8];
        bQ0[c] = *(const bf16x8*)qp;
        bQ1[c] = *(const bf16x8*)(qp + 32);
    }

    bf16x8 vONE;
#pragma unroll
    for (int i = 0; i < 8; i++) vONE[i] = (bf16)1.0f;

    // staging: each thread owns one row (kr) and two adjacent 16B chunks.
    int cc0 = tid * 2, cc1 = cc0 + 1;
    int kr0 = cc0 >> 3, kc0 = (cc0 & 7) * 8;   // global col (elems)
    int kr1 = cc1 >> 3, kc1 = (cc1 & 7) * 8;   // kr1 == kr0
    // swizzled LDS elem offsets (write side): chunk ^= row&7
    int krr7 = kr0 & 7;
    int sw0 = kr0 * 64 + (((cc0 & 7) ^ krr7) << 3);
    int sw1 = kr0 * 64 + (((cc1 & 7) ^ krr7) << 3);

    // frag-read swizzle (read side): row&7 == l15&7 for rows t*16+l15
    int r7q = l15 & 7;
    int e0 = ((quad ^ r7q) << 3);   // chunk quad   -> elems
    int e1 = e0 ^ 32;               // chunk quad+4 -> elems

    f32x4 lacc[2] = {};
    f32x4 Oacc[2][4] = {};

    {
        uint4 ka0 = *(const uint4*)&Kh[(size_t)kr0 * DHEAD + kc0];
        uint4 ka1 = *(const uint4*)&Kh[(size_t)kr1 * DHEAD + kc1];
        uint4 va0 = *(const uint4*)&Vh[(size_t)kr0 * SEQ + kc0];
        uint4 va1 = *(const uint4*)&Vh[(size_t)kr1 * SEQ + kc1];
        *(uint4*)&Ks[0][sw0] = ka0;
        *(uint4*)&Ks[0][sw1] = ka1;
        *(uint4*)&Vs[0][sw0] = va0;
        *(uint4*)&Vs[0][sw1] = va1;
    }
    __syncthreads();

#define ATTN_STEP(CUR, NXT, KB, PF)                                          \
    {                                                                        \
        uint4 nk0, nk1, nv0, nv1;                                            \
        if (PF) {                                                            \
            nk0 = *(const uint4*)&Kh[(size_t)((KB) + kr0) * DHEAD + kc0];    \
            nk1 = *(const uint4*)&Kh[(size_t)((KB) + kr1) * DHEAD + kc1];    \
            nv0 = *(const uint4*)&Vh[(size_t)kr0 * SEQ + (KB) + kc0];        \
            nv1 = *(const uint4*)&Vh[(size_t)kr1 * SEQ + (KB) + kc1];        \
        }                                                                    \
        bf16x8 aK0[4], aK1[4], bV0[4], bV1[4];                               \
        _Pragma("unroll")                                                    \
        for (int t = 0; t < 4; t++) {                                        \
            const bf16* kp = &Ks[CUR][(t * 16 + l15) * 64];                  \
            aK0[t] = *(const bf16x8*)(kp + e0);                              \
            aK1[t] = *(const bf16x8*)(kp + e1);                              \
            const bf16* vp = &Vs[CUR][(t * 16 + l15) * 64];                  \
            bV0[t] = *(const bf16x8*)(vp + e0);                              \
            bV1[t] = *(const bf16x8*)(vp + e1);                              \
        }                                                                    \
        _Pragma("unroll")                                                    \
        for (int c = 0; c < 2; c++) {                                        \
            __builtin_amdgcn_s_setprio(1);                                   \
            f32x4 st[4];                                                     \
            _Pragma("unroll")                                                \
            for (int t = 0; t < 4; t++) {                                    \
                f32x4 zv = {0.f, 0.f, 0.f, 0.f};                             \
                st[t] = mfma16(aK1[t], bQ1[c], mfma16(aK0[t], bQ0[c], zv));  \
            }                                                                \
            bf16* myP = Pb[wid];                                             \
            _Pragma("unroll")                                                \
            for (int t = 0; t < 4; t++) {                                    \
                bf16x4 pk;                                                   \
                _Pragma("unroll")                                            \
                for (int r = 0; r < 4; r++)                                  \
                    pk[r] = (bf16)__builtin_amdgcn_exp2f(                    \
                                fminf(st[t][r], 60.f));                      \
                int pch = ((2 * t + (quad >> 1)) ^ r7q) << 3;                \
                *(bf16x4*)&myP[l15 * 64 + pch + ((quad & 1) << 2)] = pk;     \
            }                                                                \
            bf16x8 aP0 = *(const bf16x8*)&myP[l15 * 64 + e0];                \
            bf16x8 aP1 = *(const bf16x8*)&myP[l15 * 64 + e1];                \
            _Pragma("unroll")                                                \
            for (int nt = 0; nt < 4; nt++)                                   \
                Oacc[c][nt] = mfma16(aP1, bV1[nt],                           \
                                     mfma16(aP0, bV0[nt], Oacc[c][nt]));     \
            lacc[c] = mfma16(aP1, vONE, mfma16(aP0, vONE, lacc[c]));         \
            __builtin_amdgcn_s_setprio(0);                                   \
        }                                                                    \
        if (PF) {                                                            \
            *(uint4*)&Ks[NXT][sw0] = nk0;                                    \
            *(uint4*)&Ks[NXT][sw1] = nk1;                                    \
            *(uint4*)&Vs[NXT][sw0] = nv0;                                    \
            *(uint4*)&Vs[NXT][sw1] = nv1;                                    \
        }                                                                    \
        __syncthreads();                                                     \
    }

    for (int it2 = 0; it2 < SEQ / 128; it2++) {
        ATTN_STEP(0, 1, (2 * it2 + 1) * 64, true);
        ATTN_STEP(1, 0, (2 * it2 + 2) * 64, (it2 + 1 < SEQ / 128));
    }
#undef ATTN_STEP

    int b = bh >> 3, hd = bh & 7;
#pragma unroll
    for (int c = 0; c < 2; c++) {
        float linv[4];
#pragma unroll
        for (int r = 0; r < 4; r++)
            linv[r] = 1.f / lacc[c][r];
#pragma unroll
        for (int nt = 0; nt < 4; nt++)
#pragma unroll
            for (int r = 0; r < 4; r++) {
                int s = qb + c * 16 + quad * 4 + r;
                Out[((size_t)(b * SEQ + s)) * DMODEL + hd * 64 + nt * 16 + l15]
                    = (bf16)(Oacc[c][nt][r] * linv[r]);
            }
    }
}

// ---------------------------------------------------------------------------
// Residual + LayerNorm (unbiased std ddof=1, eps added to std).
// ---------------------------------------------------------------------------
__global__ __launch_bounds__(256) void ln_kernel(
        const bf16* __restrict__ X, const bf16* __restrict__ T,
        const bf16* __restrict__ Al, const bf16* __restrict__ Bl,
        void* __restrict__ Out, int final_out) {
    int wid = threadIdx.x >> 6, lane = threadIdx.x & 63;
    int row = blockIdx.x * 4 + wid;
    const bf16* xr = X + (size_t)row * DMODEL;
    const bf16* tr = T + (size_t)row * DMODEL;
    bf16x8 xv = *(const bf16x8*)&xr[lane * 8];
    bf16x8 tv = *(const bf16x8*)&tr[lane * 8];
    float v[8];
#pragma unroll
    for (int i = 0; i < 8; i++) v[i] = (float)xv[i] + (float)tv[i];
    float sum = 0.f, sq = 0.f;
#pragma unroll
    for (int i = 0; i < 8; i++) { sum += v[i]; sq += v[i] * v[i]; }
#pragma unroll
    for (int m = 1; m < 64; m <<= 1) {
        sum += __shfl_xor(sum, m);
        sq  += __shfl_xor(sq,  m);
    }
    float mean = sum * (1.f / DMODEL);
    float var  = (sq - DMODEL * mean * mean) * (1.f / (DMODEL - 1));
    var = var > 0.f ? var : 0.f;
    float inv = 1.f / (sqrtf(var) + 1e-6f);
#pragma unroll
    for (int i = 0; i < 8; i++) {
        int c = lane * 8 + i;
        float yv = (float)Al[c] * (v[i] - mean) * inv + (float)Bl[c];
        yv = fminf(fmaxf(yv, -1e4f), 1e4f);
        size_t idx = (size_t)row * DMODEL + c;
        if (final_out) ((float*)Out)[idx] = yv;
        else           ((bf16*)Out)[idx]  = (bf16)yv;
    }
}

// ---------------------------------------------------------------------------
extern "C" void kernel_launch(void* const* d_in, const int* in_sizes, int n_in,
                              void* d_out, int out_size, void* d_ws, size_t ws_size,
                              hipStream_t stream) {
    if (ws_size < WS_NEED) {
        sentinel_kernel<<<1, 64, 0, stream>>>((bf16*)d_out);
        return;
    }

    const float* x  = (const float*)d_in[0];
    const float* wq = (const float*)d_in[1],  *bq = (const float*)d_in[2];
    const float* wk = (const float*)d_in[3],  *bk = (const float*)d_in[4];
    const float* wv = (const float*)d_in[5],  *bv = (const float*)d_in[6];
    const float* wo = (const float*)d_in[7],  *bo = (const float*)d_in[8];
    const float* w1 = (const float*)d_in[9],  *b1 = (const float*)d_in[10];
    const float* w2 = (const float*)d_in[11], *b2 = (const float*)d_in[12];
    const float* ln1a = (const float*)d_in[13], *ln1b = (const float*)d_in[14];
    const float* ln2a = (const float*)d_in[15], *ln2b = (const float*)d_in[16];

    char* ws = (char*)d_ws;
    bf16* wT   = (bf16*)(ws + 0);
    bf16* woT  = (bf16*)(ws + 1572864);
    bf16* w1T  = (bf16*)(ws + 2097152);
    bf16* w2T  = (bf16*)(ws + 4194304);
    bf16* xcv  = (bf16*)(ws + 6291456);
    bf16* prm  = (bf16*)(ws + 14680064);
    bf16* regA = (bf16*)(ws + 14696448);
    bf16* regB = (bf16*)(ws + 23085056);
    bf16* regC = (bf16*)(ws + 31473664);
    bf16* ff1  = (bf16*)(ws + 39862272);
    bf16* aout = (bf16*)d_out;   // scratch (fully overwritten by final LN)

    bf16 *pbq = prm, *pbo = prm + 1536;
    bf16 *pb1 = prm + 2048, *pb2 = prm + 4096;
    bf16 *pl1a = prm + 4608, *pl1b = prm + 5120;
    bf16 *pl2a = prm + 5632, *pl2b = prm + 6144;

    prep_kernel<<<7178, 256, 0, stream>>>(x, wq, wk, wv, wo, w1, w2,
                                          bq, bk, bv, bo, b1, b2,
                                          ln1a, ln1b, ln2a, ln2b,
                                          xcv, wT, w1T, w2T, prm);

    // fused QKV projection (Q pre-scaled by QSCALE; V^T coalesced epilogue)
    gemm_qkv<<<dim3(64, 12), 256, 0, stream>>>(xcv, wT, pbq,
                                               regA, regB, regC,
                                               MTOT, 3 * DMODEL, DMODEL);

    // attention -> d_out (scratch), direct bf16
    attn_kernel<<<dim3(SEQ / 128, NBATCH * NHEADS), 256, 0, stream>>>(
        regA, regB, regC, aout);

    // O-proj: aout -> t (regA); BM=64/BK=64
    gemm_bt64<false><<<dim3(128, 4), 256, 0, stream>>>(aout, woT, pbo, regA,
                                                       MTOT, DMODEL, DMODEL);

    // LN1: xcv + t -> y (regB)
    ln_kernel<<<MTOT / 4, 256, 0, stream>>>(xcv, regA, pl1a, pl1b, regB, 0);

    // FFN: y -> ff1 -> ff2 (regA)
    gemm_bt<true ><<<dim3(64, 16), 256, 0, stream>>>(regB, w1T, pb1, ff1,
                                                     MTOT, DFF, DMODEL);
    gemm_bt64<false><<<dim3(128, 4), 256, 0, stream>>>(ff1, w2T, pb2, regA,
                                                       MTOT, DMODEL, DFF);

    // LN2: y + ff2 -> out (fp32)
    ln_kernel<<<MTOT / 4, 256, 0, stream>>>(regB, regA, pl2a, pl2b, d_out, 1);
}